// Round 14
// baseline (2513.224 us; speedup 1.0000x reference)
//
#include <hip/hip_runtime.h>

// TV denoiser (Chambolle-Pock), 40 iterations.
// PRIMARY: one persistent cooperative kernel, 5 rounds x 8 fused steps with
// a grid barrier between rounds; x2/u/y live in registers across rounds;
// only the outer-8 band/ring crosses global memory between rounds.
// FALLBACK: if hipLaunchCooperativeKernel is rejected (round-13 failure mode:
// silent no-op, absmax == max|ref|), run the verified round-12 5-launch path.
//
// Round-13 diagnosis: coop launch rejected (output all zeros, no deadlock).
// Likely occupancy: __launch_bounds__(512,4) caps VGPR at 128 (waves/EU
// semantics) -> ~3 blocks/CU -> 768 < 968 grid. Fix: (512,8) caps VGPR at 64
// under EITHER semantics -> 4 blocks/CU -> capacity 1024 >= 968. Register
// state slimmed to ~55: tm[]/ehf[] arrays dropped (row terms of the cone
// mask are wave-uniform scalars; per-lane part is one compare vs
// mc = min(lc,63-lc)).
//
// Shared geometry (verified round 12): 512 thr = 8 waves; wave s owns rows
// 8s..8s+7 of a 64x64 staged region (1 col x 8 rows per thread, registers);
// interior 48x48. Horizontal exchange via __shfl (DPP wave-shift mis-shifts
// on gfx950 -- round-11 fail). Strip boundaries via tiny LDS (conflict-free).
// Phase 1 unconditional (cone argument); phase 2 selects freeze inactive/OOB
// cells exactly (round-2 invariant).

#define Hh 512
#define Ww 512
#define Bb 8
#define TS 48
#define KF 8
#define S  64
#define NT 512
#define RS 8
#define NBLK (11 * 11 * 8)   // 968

// ---------------------------------------------------------------- persistent
__device__ __forceinline__ void grid_barrier(unsigned* ctr, unsigned target)
{
    __threadfence();                     // release: publish band stores
    __syncthreads();
    if (threadIdx.x == 0) {
        __hip_atomic_fetch_add(ctr, 1u, __ATOMIC_ACQ_REL, __HIP_MEMORY_SCOPE_AGENT);
        unsigned v;
        do {
            __builtin_amdgcn_s_sleep(8);
            v = __hip_atomic_load(ctr, __ATOMIC_ACQUIRE, __HIP_MEMORY_SCOPE_AGENT);
        } while (v < target);
    }
    __syncthreads();
    __threadfence();                     // acquire: drop stale cached lines
}

__global__ __launch_bounds__(NT, 8)
void tv_persist(const float*  __restrict__ y_in,
                float*  __restrict__ x2S,
                float2* __restrict__ uS,
                float*  __restrict__ out,
                unsigned* __restrict__ ctr)
{
    constexpr float TAU = 0.01f;
    constexpr float RHO = 1.99f;
    constexpr float SIGMA = 12.5f;
    constexpr float THS = 0.1f;
    constexpr float INV_1PT = 1.0f / 1.01f;

    __shared__ float u0B [9 * S];
    __shared__ float wTop[9 * S];

    const int b   = blockIdx.z;
    const int r0  = blockIdx.y * TS;
    const int c0  = blockIdx.x * TS;
    const int tid = threadIdx.x;
    const size_t plane = (size_t)b * (Hh * Ww);

    const int s   = tid >> 6;                 // wave id (uniform per wave)
    const int lc  = tid & 63;                 // lane id
    const int gc  = c0 - KF + lc;
    const bool colin = (gc >= 0) & (gc < Ww);
    const float ewf = (gc < Ww - 1) ? 1.f : 0.f;
    const int lr0 = RS * s;
    const int gr0 = r0 - KF + lr0;            // wave-uniform
    const int mc  = min(lc, 63 - lc);         // per-lane cone bound
    const bool colring  = (lc < KF) | (lc >= KF + TS);
    const bool rowringS = (s == 0) | (s == 7);

    if (tid < S) { u0B[tid] = 0.f; wTop[8 * S + tid] = 0.f; }

    float u0[RS], u1[RS], x2[RS], yv[RS], w[RS];

    // ---- initial stage: y only; x2 = y, u = 0
    #pragma unroll
    for (int i = 0; i < RS; ++i) {
        const int gr = gr0 + i;
        const bool img = colin & (gr >= 0) & (gr < Hh);
        float c = img ? y_in[plane + (size_t)gr * Ww + gc] : 0.f;
        yv[i] = c; x2[i] = c; u0[i] = 0.f; u1[i] = 0.f;
    }

    for (int r = 0; r < 5; ++r) {
        if (r > 0) {
            // ---- reload outer-8 ring (written as neighbors' bands)
            #pragma unroll
            for (int i = 0; i < RS; ++i) {
                if (rowringS | colring) {
                    const int gr = gr0 + i;
                    const bool img = colin & (gr >= 0) & (gr < Hh);
                    float a = 0.f, z0 = 0.f, z1 = 0.f;
                    if (img) {
                        size_t gi = plane + (size_t)gr * Ww + gc;
                        a = x2S[gi];
                        float2 uu = uS[gi];
                        z0 = uu.x; z1 = uu.y;
                    }
                    x2[i] = a; u0[i] = z0; u1[i] = z1;
                }
            }
        }
        u0B[(s + 1) * S + lc] = u0[RS - 1];
        __syncthreads();

        for (int t = 0; t < KF; ++t) {
            // ---- phase 1: w = 2x - x2 (unconditional; cone argument)
            {
                float u0a = u0B[s * S + lc];
                #pragma unroll
                for (int i = 0; i < RS; ++i) {
                    float ul = __shfl_up(u1[i], 1, 64);
                    float ua = (i == 0) ? u0a : u0[i - 1];
                    float adj = ua - u0[i] + ul - u1[i];
                    float xv = fmaf(TAU, yv[i] - adj, x2[i]);
                    w[i] = fmaf(2.0f * INV_1PT, xv, -x2[i]);
                }
                wTop[s * S + lc] = w[0];
            }
            __syncthreads();
            // ---- phase 2: u, x2 update; selects freeze inactive/OOB cells
            {
                float wbot = wTop[(s + 1) * S + lc];
                #pragma unroll
                for (int i = 0; i < RS; ++i) {
                    const int gr = gr0 + i;              // uniform
                    const int lr = lr0 + i;              // uniform
                    float wr = __shfl_down(w[i], 1, 64);
                    float wb = (i == RS - 1) ? wbot : w[i + 1];
                    float eh = (gr < Hh - 1) ? 1.f : 0.f;
                    float dh = eh * (wb - w[i]);
                    float dw = ewf * (wr - w[i]);
                    float v0 = fmaf(SIGMA, dh, u0[i]);
                    float v1 = fmaf(SIGMA, dw, u1[i]);
                    float iv = fminf(THS * __builtin_amdgcn_rsqf(fmaf(v0, v0, v1 * v1)), 1.f);
                    bool a = colin & (t < mc) & (gr >= 0) & (gr < Hh)
                           & (t < min(lr, S - 1 - lr));
                    u0[i] = a ? fmaf(RHO, v0 * iv - u0[i], u0[i]) : u0[i];
                    u1[i] = a ? fmaf(RHO, v1 * iv - u1[i], u1[i]) : u1[i];
                    x2[i] = a ? fmaf(0.5f * RHO, w[i] - x2[i], x2[i]) : x2[i];
                }
                u0B[(s + 1) * S + lc] = u0[RS - 1];
            }
            __syncthreads();
        }

        if (r < 4) {
            // ---- store outer-8 band of the interior (all neighbors read)
            if (s >= 1 && s <= 6 && !colring && gc < Ww) {
                const bool colband = (lc < 2 * KF) | (lc >= TS);
                const bool rowband = (s == 1) | (s == 6);
                if (colband | rowband) {
                    #pragma unroll
                    for (int i = 0; i < RS; ++i) {
                        const int gr = gr0 + i;
                        if (gr < Hh) {
                            size_t gi = plane + (size_t)gr * Ww + gc;
                            x2S[gi] = x2[i];
                            uS[gi]  = make_float2(u0[i], u1[i]);
                        }
                    }
                }
            }
            grid_barrier(ctr, (unsigned)(NBLK * (r + 1)));
        } else {
            if (s >= 1 && s <= 6 && !colring && gc < Ww) {
                #pragma unroll
                for (int i = 0; i < RS; ++i) {
                    const int gr = gr0 + i;
                    if (gr < Hh)
                        out[plane + (size_t)gr * Ww + gc] = x2[i];
                }
            }
        }
    }
}

// ---------------------------------------------------------------- fallback
// Verified round-12 kernel (PASS, 234 us).
__global__ __launch_bounds__(NT, 2)
void tv_fused(const float*  __restrict__ x2_in,
              const float2* __restrict__ u_in,
              const float*  __restrict__ y_in,
              float*  __restrict__ x2_out,
              float2* __restrict__ u_out,
              int first, int last)
{
    constexpr float TAU = 0.01f;
    constexpr float RHO = 1.99f;
    constexpr float SIGMA = 12.5f;
    constexpr float THS = 0.1f;
    constexpr float INV_1PT = 1.0f / 1.01f;

    __shared__ float u0B [9 * S];
    __shared__ float wTop[9 * S];

    const int b   = blockIdx.z;
    const int r0  = blockIdx.y * TS;
    const int c0  = blockIdx.x * TS;
    const int tid = threadIdx.x;
    const size_t plane = (size_t)b * (Hh * Ww);

    const int s   = tid >> 6;
    const int lc  = tid & 63;
    const int gc  = c0 - KF + lc;
    const bool colin = (gc >= 0) & (gc < Ww);
    const float ewf = (gc < Ww - 1) ? 1.f : 0.f;
    const int lr0 = RS * s;
    const int gr0 = r0 - KF + lr0;

    if (tid < S) { u0B[tid] = 0.f; wTop[8 * S + tid] = 0.f; }

    float u0[RS], u1[RS], x2[RS], yv[RS], w[RS], ehf[RS];
    int   tm[RS];

    #pragma unroll
    for (int i = 0; i < RS; ++i) {
        const int gr = gr0 + i;
        const int lr = lr0 + i;
        const bool img = colin & (gr >= 0) & (gr < Hh);
        float a = 0.f, c = 0.f, z0 = 0.f, z1 = 0.f;
        if (img) {
            size_t gi = plane + (size_t)gr * Ww + gc;
            c = y_in[gi];
            if (first) a = c;
            else {
                a = x2_in[gi];
                float2 uu = u_in[gi];
                z0 = uu.x; z1 = uu.y;
            }
        }
        u0[i] = z0; u1[i] = z1; x2[i] = a; yv[i] = c;
        ehf[i] = (gr < Hh - 1) ? 1.f : 0.f;
        tm[i] = img ? min(min(lr, S - 1 - lr), min(lc, S - 1 - lc)) : 0;
    }
    u0B[(s + 1) * S + lc] = u0[RS - 1];
    __syncthreads();

    for (int t = 0; t < KF; ++t) {
        {
            float u0a = u0B[s * S + lc];
            #pragma unroll
            for (int i = 0; i < RS; ++i) {
                float ul = __shfl_up(u1[i], 1, 64);
                float ua = (i == 0) ? u0a : u0[i - 1];
                float adj = ua - u0[i] + ul - u1[i];
                float xv = fmaf(TAU, yv[i] - adj, x2[i]);
                w[i] = fmaf(2.0f * INV_1PT, xv, -x2[i]);
            }
            wTop[s * S + lc] = w[0];
        }
        __syncthreads();
        {
            float wbot = wTop[(s + 1) * S + lc];
            #pragma unroll
            for (int i = 0; i < RS; ++i) {
                float wr = __shfl_down(w[i], 1, 64);
                float wb = (i == RS - 1) ? wbot : w[i + 1];
                float dh = ehf[i] * (wb - w[i]);
                float dw = ewf * (wr - w[i]);
                float v0 = fmaf(SIGMA, dh, u0[i]);
                float v1 = fmaf(SIGMA, dw, u1[i]);
                float iv = fminf(THS * __builtin_amdgcn_rsqf(fmaf(v0, v0, v1 * v1)), 1.f);
                bool a = t < tm[i];
                u0[i] = a ? fmaf(RHO, v0 * iv - u0[i], u0[i]) : u0[i];
                u1[i] = a ? fmaf(RHO, v1 * iv - u1[i], u1[i]) : u1[i];
                x2[i] = a ? fmaf(0.5f * RHO, w[i] - x2[i], x2[i]) : x2[i];
            }
            u0B[(s + 1) * S + lc] = u0[RS - 1];
        }
        __syncthreads();
    }

    if (s >= 1 && s <= 6 && lc >= KF && lc < KF + TS && gc < Ww) {
        #pragma unroll
        for (int i = 0; i < RS; ++i) {
            const int gr = gr0 + i;
            if (gr < Hh) {
                size_t gi = plane + (size_t)gr * Ww + gc;
                x2_out[gi] = x2[i];
                if (!last) u_out[gi] = make_float2(u0[i], u1[i]);
            }
        }
    }
}

extern "C" void kernel_launch(void* const* d_in, const int* in_sizes, int n_in,
                              void* d_out, int out_size, void* d_ws, size_t ws_size,
                              hipStream_t stream)
{
    const float* y = (const float*)d_in[0];
    float* out = (float*)d_out;
    const size_t NP = (size_t)Bb * Hh * Ww;   // 2M cells

    float* ws = (float*)d_ws;
    // fallback buffers (round 12)
    float*  x2A = ws;
    float*  x2B = ws + NP;
    float2* uA  = (float2*)(ws + 2 * NP);
    float2* uB  = (float2*)(ws + 4 * NP);
    // persistent-path buffers (overlap fallback's; never used in same call)
    float*    x2S = ws;
    float2*   uS  = (float2*)(ws + NP);
    unsigned* ctr = (unsigned*)(ws + 5 * NP);  // inside uB span; unused by persist path otherwise

    hipMemsetAsync(ctr, 0, 128, stream);

    dim3 grid(11, 11, 8), block(NT);
    void* args[] = { (void*)&y, (void*)&x2S, (void*)&uS, (void*)&out, (void*)&ctr };
    hipError_t e = hipLaunchCooperativeKernel((void*)tv_persist, grid, block, args, 0, stream);

    if (e != hipSuccess) {
        // verified round-12 path (234 us)
        tv_fused<<<grid, block, 0, stream>>>(y,   uB, y, x2A, uA, 1, 0);
        tv_fused<<<grid, block, 0, stream>>>(x2A, uA, y, x2B, uB, 0, 0);
        tv_fused<<<grid, block, 0, stream>>>(x2B, uB, y, x2A, uA, 0, 0);
        tv_fused<<<grid, block, 0, stream>>>(x2A, uA, y, x2B, uB, 0, 0);
        tv_fused<<<grid, block, 0, stream>>>(x2B, uB, y, out, uA, 0, 1);
    }
}